// Round 1
// baseline (1364.765 us; speedup 1.0000x reference)
//
#include <hip/hip_runtime.h>
#include <hip/hip_bf16.h>

// ---------------------------------------------------------------------------
// TransformerBlock: B=2 N=2048 E=2048 H=16 G=4 D=128 HID=8192
// out = [ x2 (8.39M f32) | k_flat (8.39M) | v_flat (8.39M) | attn (134.2M) ]
// ---------------------------------------------------------------------------

using f32x4  = __attribute__((ext_vector_type(4))) float;
using bf16x8 = __attribute__((ext_vector_type(8))) short;
using u16x4  = __attribute__((ext_vector_type(4))) unsigned short;

#define DEV __device__ __forceinline__

DEV unsigned short f2bf(float f) {
  unsigned int u = __float_as_uint(f);
  return (unsigned short)((u + 0x7fffu + ((u >> 16) & 1u)) >> 16);
}
DEV float bf2f(unsigned short h) {
  return __uint_as_float(((unsigned int)h) << 16);
}

DEV float waveRedMax(float v) {
#pragma unroll
  for (int o = 32; o; o >>= 1) v = fmaxf(v, __shfl_xor(v, o));
  return v;
}
DEV float waveRedSum(float v) {
#pragma unroll
  for (int o = 32; o; o >>= 1) v += __shfl_xor(v, o);
  return v;
}

// ---- transpose+convert: in f32 [K,N] -> out bf16 [N,K] ---------------------
__global__ __launch_bounds__(256) void kconvT(const float* __restrict__ in,
                                              unsigned short* __restrict__ out,
                                              int K, int N) {
  __shared__ float tile[32][33];
  int bx = blockIdx.x * 32;  // N dim
  int by = blockIdx.y * 32;  // K dim
  int tx = threadIdx.x & 31;
  int ty = threadIdx.x >> 5;  // 0..7
#pragma unroll
  for (int i = 0; i < 32; i += 8)
    tile[ty + i][tx] = in[(size_t)(by + ty + i) * N + bx + tx];
  __syncthreads();
#pragma unroll
  for (int i = 0; i < 32; i += 8)
    out[(size_t)(bx + ty + i) * K + by + tx] = f2bf(tile[tx][ty + i]);
}

// ---- v_flat = x (f32 copy) and x_bf16 --------------------------------------
__global__ __launch_bounds__(256) void kcopy(const f32x4* __restrict__ x,
                                             f32x4* __restrict__ v,
                                             u16x4* __restrict__ xb) {
  int i = blockIdx.x * 256 + threadIdx.x;  // exactly 2,097,152 threads
  f32x4 val = x[i];
  v[i] = val;
  u16x4 o;
  o[0] = f2bf(val[0]); o[1] = f2bf(val[1]); o[2] = f2bf(val[2]); o[3] = f2bf(val[3]);
  xb[i] = o;
}

// ---- RoPE on per-head slices of x -> k_flat f32 (d_out) + xq bf16 ----------
__global__ __launch_bounds__(256) void krope(const float* __restrict__ x,
                                             float* __restrict__ kout,
                                             unsigned short* __restrict__ xq) {
  int idx = blockIdx.x * 256 + threadIdx.x;  // B*N*H*64 = 4,194,304
  int f  = idx & 63;
  int h  = (idx >> 6) & 15;
  int bn = idx >> 10;          // b*2048+n
  int n  = bn & 2047;
  size_t base = (size_t)bn * 2048 + h * 128;
  float inv = powf(10000.0f, -(float)f * (1.0f / 64.0f));
  float ang = (float)n * inv;
  float c = cosf(ang), s = sinf(ang);
  float a = x[base + f], b = x[base + f + 64];
  float k1 = a * c - b * s;
  float k2 = b * c + a * s;
  kout[base + f]      = k1;
  kout[base + f + 64] = k2;
  xq[base + f]      = f2bf(k1);
  xq[base + f + 64] = f2bf(k2);
}

// ---- row softmax in-place, row = 2048 f32 ----------------------------------
__global__ __launch_bounds__(256) void ksoftmax(float* __restrict__ attn) {
  float* p = attn + (size_t)blockIdx.x * 2048;
  int tid = threadIdx.x;
  f32x4* p4 = (f32x4*)p;
  f32x4 v0 = p4[tid * 2], v1 = p4[tid * 2 + 1];
  float m = -3.4e38f;
#pragma unroll
  for (int i = 0; i < 4; ++i) { m = fmaxf(m, v0[i]); m = fmaxf(m, v1[i]); }
  m = waveRedMax(m);
  __shared__ float red[8];
  int wid = tid >> 6, lane = tid & 63;
  if (!lane) red[wid] = m;
  __syncthreads();
  m = fmaxf(fmaxf(red[0], red[1]), fmaxf(red[2], red[3]));
  float s = 0.f;
#pragma unroll
  for (int i = 0; i < 4; ++i) {
    v0[i] = expf(v0[i] - m); s += v0[i];
    v1[i] = expf(v1[i] - m); s += v1[i];
  }
  s = waveRedSum(s);
  if (!lane) red[4 + wid] = s;
  __syncthreads();
  s = red[4] + red[5] + red[6] + red[7];
  float invs = 1.0f / s;
  p4[tid * 2]     = v0 * invs;
  p4[tid * 2 + 1] = v1 * invs;
}

// ---- x1b = bf16(rmsnorm(x + ao) * w) ---------------------------------------
__global__ __launch_bounds__(256) void krms1(const float* __restrict__ x,
                                             const float* __restrict__ ao,
                                             const float* __restrict__ w,
                                             unsigned short* __restrict__ x1b) {
  size_t row = blockIdx.x;
  const f32x4* xp = (const f32x4*)(x + row * 2048);
  const f32x4* ap = (const f32x4*)(ao + row * 2048);
  int tid = threadIdx.x;
  f32x4 t0 = xp[tid * 2] + ap[tid * 2];
  f32x4 t1 = xp[tid * 2 + 1] + ap[tid * 2 + 1];
  float ss = 0.f;
#pragma unroll
  for (int i = 0; i < 4; ++i) ss += t0[i] * t0[i] + t1[i] * t1[i];
  ss = waveRedSum(ss);
  __shared__ float red[4];
  int wid = tid >> 6, lane = tid & 63;
  if (!lane) red[wid] = ss;
  __syncthreads();
  ss = red[0] + red[1] + red[2] + red[3];
  float rr = rsqrtf(ss * (1.0f / 2048.0f) + 1e-6f);
  const f32x4* wp = (const f32x4*)w;
  f32x4 w0 = wp[tid * 2], w1 = wp[tid * 2 + 1];
  u16x4 o0, o1;
#pragma unroll
  for (int i = 0; i < 4; ++i) {
    o0[i] = f2bf(t0[i] * rr * w0[i]);
    o1[i] = f2bf(t1[i] * rr * w1[i]);
  }
  u16x4* op = (u16x4*)(x1b + row * 2048);
  op[tid * 2] = o0;
  op[tid * 2 + 1] = o1;
}

// ---- x2 = f32(rmsnorm(x1b + fc) * w) -> d_out ------------------------------
__global__ __launch_bounds__(256) void krms2(const unsigned short* __restrict__ x1b,
                                             const unsigned short* __restrict__ fc,
                                             const float* __restrict__ w,
                                             float* __restrict__ out) {
  size_t row = blockIdx.x;
  const u16x4* xp = (const u16x4*)(x1b + row * 2048);
  const u16x4* fp = (const u16x4*)(fc + row * 2048);
  int tid = threadIdx.x;
  u16x4 a0 = xp[tid * 2], a1 = xp[tid * 2 + 1];
  u16x4 b0 = fp[tid * 2], b1 = fp[tid * 2 + 1];
  f32x4 t0, t1;
#pragma unroll
  for (int i = 0; i < 4; ++i) {
    t0[i] = bf2f(a0[i]) + bf2f(b0[i]);
    t1[i] = bf2f(a1[i]) + bf2f(b1[i]);
  }
  float ss = 0.f;
#pragma unroll
  for (int i = 0; i < 4; ++i) ss += t0[i] * t0[i] + t1[i] * t1[i];
  ss = waveRedSum(ss);
  __shared__ float red[4];
  int wid = tid >> 6, lane = tid & 63;
  if (!lane) red[wid] = ss;
  __syncthreads();
  ss = red[0] + red[1] + red[2] + red[3];
  float rr = rsqrtf(ss * (1.0f / 2048.0f) + 1e-6f);
  const f32x4* wp = (const f32x4*)w;
  f32x4 w0 = wp[tid * 2], w1 = wp[tid * 2 + 1];
  f32x4* op = (f32x4*)(out + row * 2048);
  op[tid * 2]     = t0 * rr * w0;
  op[tid * 2 + 1] = t1 * rr * w1;
}

// ---- generic 128x128 MFMA GEMM: C = alpha * A[M,K] @ BT[N,K]^T -------------
// Batched over z: b = z>>4, h = z&15; per-operand offsets.
template <bool A_F32, bool OUT_BF16, bool TRANS_OUT>
__global__ __launch_bounds__(256, 2) void gemm_bt(
    const void* __restrict__ A_, const unsigned short* __restrict__ Bt,
    void* __restrict__ C_, int K, int lda, int ldb, int ldc,
    long long oAb, long long oAh, long long oBb, long long oBg,
    long long oCb, long long oCh, float alpha) {
  __shared__ unsigned short As[128 * 32];
  __shared__ unsigned short Bs[128 * 32];
  const int tid = threadIdx.x;
  const int z = blockIdx.z, bz = z >> 4, hz = z & 15;
  const int bm0 = blockIdx.y * 128, bn0 = blockIdx.x * 128;
  const size_t offA = (size_t)(bz * oAb + hz * oAh);
  const size_t offB = (size_t)(bz * oBb + (hz >> 2) * oBg);
  const size_t offC = (size_t)(bz * oCb + hz * oCh);
  const unsigned short* Ab = (const unsigned short*)A_ + offA;
  const float* Af = (const float*)A_ + offA;
  const unsigned short* Bb = Bt + offB;

  f32x4 acc[4][4] = {};

  const int lane = tid & 63, wid = tid >> 6;
  const int wr = wid >> 1, wc = wid & 1;
  const int lr = lane & 15, kq = lane >> 4;
  const int srow = tid >> 2;        // 0..63
  const int scol = (tid & 3) * 8;   // 0,8,16,24

  for (int kt = 0; kt < K; kt += 32) {
#pragma unroll
    for (int r = 0; r < 2; ++r) {
      int row = srow + 64 * r;
      if constexpr (!A_F32) {
        *(bf16x8*)&As[row * 32 + scol] =
            *(const bf16x8*)(Ab + (size_t)(bm0 + row) * lda + kt + scol);
      } else {
        const float* p = Af + (size_t)(bm0 + row) * lda + kt + scol;
        f32x4 lo = *(const f32x4*)p;
        f32x4 hi = *(const f32x4*)(p + 4);
        bf16x8 v;
        v[0] = (short)f2bf(lo[0]); v[1] = (short)f2bf(lo[1]);
        v[2] = (short)f2bf(lo[2]); v[3] = (short)f2bf(lo[3]);
        v[4] = (short)f2bf(hi[0]); v[5] = (short)f2bf(hi[1]);
        v[6] = (short)f2bf(hi[2]); v[7] = (short)f2bf(hi[3]);
        *(bf16x8*)&As[row * 32 + scol] = v;
      }
      *(bf16x8*)&Bs[row * 32 + scol] =
          *(const bf16x8*)(Bb + (size_t)(bn0 + row) * ldb + kt + scol);
    }
    __syncthreads();
    bf16x8 afr[4], bfr[4];
#pragma unroll
    for (int i = 0; i < 4; ++i)
      afr[i] = *(const bf16x8*)&As[(wr * 64 + i * 16 + lr) * 32 + kq * 8];
#pragma unroll
    for (int j = 0; j < 4; ++j)
      bfr[j] = *(const bf16x8*)&Bs[(wc * 64 + j * 16 + lr) * 32 + kq * 8];
#pragma unroll
    for (int i = 0; i < 4; ++i)
#pragma unroll
      for (int j = 0; j < 4; ++j)
        acc[i][j] = __builtin_amdgcn_mfma_f32_16x16x32_bf16(afr[i], bfr[j],
                                                            acc[i][j], 0, 0, 0);
    __syncthreads();
  }

#pragma unroll
  for (int i = 0; i < 4; ++i)
#pragma unroll
    for (int j = 0; j < 4; ++j) {
      int rowb = bm0 + wr * 64 + i * 16 + kq * 4;
      int col = bn0 + wc * 64 + j * 16 + lr;
#pragma unroll
      for (int r = 0; r < 4; ++r) {
        float v = acc[i][j][r] * alpha;
        size_t idx = TRANS_OUT ? ((size_t)col * ldc + (rowb + r))
                               : ((size_t)(rowb + r) * ldc + col);
        if constexpr (OUT_BF16)
          ((unsigned short*)C_)[offC + idx] = f2bf(v);
        else
          ((float*)C_)[offC + idx] = v;
      }
    }
}

// ---- fused GeGLU dual GEMM: h = (A@B1^T) * gelu(A@B2^T), bf16 out ----------
__global__ __launch_bounds__(256, 2) void gemm_geglu(
    const unsigned short* __restrict__ A, const unsigned short* __restrict__ B1,
    const unsigned short* __restrict__ B2, unsigned short* __restrict__ H_,
    int K, int lda, int ldb, int ldc) {
  __shared__ unsigned short As[128 * 32];
  __shared__ unsigned short B1s[128 * 32];
  __shared__ unsigned short B2s[128 * 32];
  const int tid = threadIdx.x;
  const int bm0 = blockIdx.y * 128, bn0 = blockIdx.x * 128;

  f32x4 accu[4][4] = {};
  f32x4 accg[4][4] = {};

  const int lane = tid & 63, wid = tid >> 6;
  const int wr = wid >> 1, wc = wid & 1;
  const int lr = lane & 15, kq = lane >> 4;
  const int srow = tid >> 2;
  const int scol = (tid & 3) * 8;

  for (int kt = 0; kt < K; kt += 32) {
#pragma unroll
    for (int r = 0; r < 2; ++r) {
      int row = srow + 64 * r;
      *(bf16x8*)&As[row * 32 + scol] =
          *(const bf16x8*)(A + (size_t)(bm0 + row) * lda + kt + scol);
      *(bf16x8*)&B1s[row * 32 + scol] =
          *(const bf16x8*)(B1 + (size_t)(bn0 + row) * ldb + kt + scol);
      *(bf16x8*)&B2s[row * 32 + scol] =
          *(const bf16x8*)(B2 + (size_t)(bn0 + row) * ldb + kt + scol);
    }
    __syncthreads();
    bf16x8 afr[4], b1fr[4], b2fr[4];
#pragma unroll
    for (int i = 0; i < 4; ++i)
      afr[i] = *(const bf16x8*)&As[(wr * 64 + i * 16 + lr) * 32 + kq * 8];
#pragma unroll
    for (int j = 0; j < 4; ++j) {
      b1fr[j] = *(const bf16x8*)&B1s[(wc * 64 + j * 16 + lr) * 32 + kq * 8];
      b2fr[j] = *(const bf16x8*)&B2s[(wc * 64 + j * 16 + lr) * 32 + kq * 8];
    }
#pragma unroll
    for (int i = 0; i < 4; ++i)
#pragma unroll
      for (int j = 0; j < 4; ++j) {
        accu[i][j] = __builtin_amdgcn_mfma_f32_16x16x32_bf16(afr[i], b1fr[j],
                                                             accu[i][j], 0, 0, 0);
        accg[i][j] = __builtin_amdgcn_mfma_f32_16x16x32_bf16(afr[i], b2fr[j],
                                                             accg[i][j], 0, 0, 0);
      }
    __syncthreads();
  }

#pragma unroll
  for (int i = 0; i < 4; ++i)
#pragma unroll
    for (int j = 0; j < 4; ++j) {
      int rowb = bm0 + wr * 64 + i * 16 + kq * 4;
      int col = bn0 + wc * 64 + j * 16 + lr;
#pragma unroll
      for (int r = 0; r < 4; ++r) {
        float u = accu[i][j][r];
        float g = accg[i][j][r];
        float t = tanhf(0.7978845608028654f * (g + 0.044715f * g * g * g));
        float hv = u * 0.5f * g * (1.0f + t);
        H_[(size_t)(rowb + r) * ldc + col] = f2bf(hv);
      }
    }
}

// ---------------------------------------------------------------------------
extern "C" void kernel_launch(void* const* d_in, const int* in_sizes, int n_in,
                              void* d_out, int out_size, void* d_ws, size_t ws_size,
                              hipStream_t stream) {
  const float* x   = (const float*)d_in[0];
  const float* wq  = (const float*)d_in[1];
  const float* wk  = (const float*)d_in[2];
  const float* wv  = (const float*)d_in[3];
  const float* wo  = (const float*)d_in[4];
  const float* w1  = (const float*)d_in[5];
  const float* w2  = (const float*)d_in[6];
  const float* n1w = (const float*)d_in[7];
  const float* n2w = (const float*)d_in[8];

  float* out    = (float*)d_out;
  float* x2_out = out;
  float* k_out  = out + 8388608;
  float* v_out  = out + 16777216;
  float* attn   = out + 25165824;  // 134,217,728 f32

  char* ws = (char*)d_ws;
  unsigned short* wqT  = (unsigned short*)(ws + 0);
  unsigned short* wkT  = (unsigned short*)(ws + 8388608);
  unsigned short* wvT  = (unsigned short*)(ws + 10485760);
  unsigned short* woT  = (unsigned short*)(ws + 12582912);
  unsigned short* w1T  = (unsigned short*)(ws + 20971520);
  unsigned short* w2T  = (unsigned short*)(ws + 88080384);
  unsigned short* qh   = (unsigned short*)(ws + 121634816);
  unsigned short* kh   = (unsigned short*)(ws + 138412032);
  unsigned short* vhT  = (unsigned short*)(ws + 142606336);
  unsigned short* ctx  = (unsigned short*)(ws + 146800640);
  float*          ao   = (float*)(ws + 163577856);
  unsigned short* hbuf = (unsigned short*)(ws + 121634816);  // alias qh..ao (dead)
  unsigned short* x1b  = (unsigned short*)(ws + 197132288);
  unsigned short* fc   = (unsigned short*)(ws + 213909504);
  // ws total: 230,686,720 bytes

  // bf16 scratch inside not-yet-written attn region of d_out
  unsigned short* xb = (unsigned short*)attn;   // bf16(x), 8,388,608 elems
  unsigned short* xq = xb + 8388608;            // bf16(rope(x))

  dim3 blk(256);

  // 1) weight convert+transpose (f32 [K,N] -> bf16 [N,K])
  kconvT<<<dim3(64, 64), blk, 0, stream>>>(wq, wqT, 2048, 2048);
  kconvT<<<dim3(16, 64), blk, 0, stream>>>(wk, wkT, 2048, 512);
  kconvT<<<dim3(16, 64), blk, 0, stream>>>(wv, wvT, 2048, 512);
  kconvT<<<dim3(64, 64), blk, 0, stream>>>(wo, woT, 2048, 2048);
  kconvT<<<dim3(512, 64), blk, 0, stream>>>(w1, w1T, 2048, 16384);
  kconvT<<<dim3(64, 256), blk, 0, stream>>>(w2, w2T, 8192, 2048);

  // 2) v_flat = x ; xb = bf16(x)
  kcopy<<<8192, blk, 0, stream>>>((const f32x4*)x, (f32x4*)v_out, (u16x4*)xb);
  // 3) k_flat = rope(x) f32 ; xq = bf16(rope(x))
  krope<<<16384, blk, 0, stream>>>(x, k_out, xq);

  // 4) projections
  gemm_bt<false, true, false><<<dim3(16, 32, 1), blk, 0, stream>>>(
      xq, wqT, qh, 2048, 2048, 2048, 2048, 0, 0, 0, 0, 0, 0, 1.0f);
  gemm_bt<false, true, false><<<dim3(4, 32, 1), blk, 0, stream>>>(
      xq, wkT, kh, 2048, 2048, 2048, 512, 0, 0, 0, 0, 0, 0, 1.0f);
  gemm_bt<false, true, true><<<dim3(4, 32, 1), blk, 0, stream>>>(
      xb, wvT, vhT, 2048, 2048, 2048, 4096, 0, 0, 0, 0, 0, 0, 1.0f);

  // 5) scores (raw -> attn region, f32), batched over (b,h)
  gemm_bt<false, false, false><<<dim3(16, 16, 32), blk, 0, stream>>>(
      qh, kh, attn, 128, 2048, 512, 2048,
      4194304LL, 128LL, 1048576LL, 128LL, 67108864LL, 4194304LL,
      0.08838834764831845f);
  // 6) softmax in-place
  ksoftmax<<<65536, blk, 0, stream>>>(attn);
  // 7) ctx = attn @ V  (A is f32, converted during staging)
  gemm_bt<true, true, false><<<dim3(1, 16, 32), blk, 0, stream>>>(
      attn, vhT, ctx, 2048, 2048, 4096, 2048,
      67108864LL, 4194304LL, 2048LL, 524288LL, 4194304LL, 128LL, 1.0f);
  // 8) attn_out = ctx @ wo (f32)
  gemm_bt<false, false, false><<<dim3(16, 32, 1), blk, 0, stream>>>(
      ctx, woT, ao, 2048, 2048, 2048, 2048, 0, 0, 0, 0, 0, 0, 1.0f);
  // 9) x1b = rmsnorm(x + ao) * n1w
  krms1<<<4096, blk, 0, stream>>>(x, ao, n1w, x1b);
  // 10) h = u * gelu(gate)  (fused dual GEMM, uv never materialized)
  gemm_geglu<<<dim3(64, 32, 1), blk, 0, stream>>>(x1b, w1T, w1T + 16777216,
                                                  hbuf, 2048, 2048, 2048, 8192);
  // 11) fc = h @ w2
  gemm_bt<false, true, false><<<dim3(16, 32, 1), blk, 0, stream>>>(
      hbuf, w2T, fc, 8192, 8192, 8192, 2048, 0, 0, 0, 0, 0, 0, 1.0f);
  // 12) x2 = rmsnorm(x1 + fc) * n2w
  krms2<<<4096, blk, 0, stream>>>(x1b, fc, n2w, x2_out);
}

// Round 2
// 1324.211 us; speedup vs baseline: 1.0306x; 1.0306x over previous
//
#include <hip/hip_runtime.h>
#include <hip/hip_bf16.h>

// ---------------------------------------------------------------------------
// TransformerBlock: B=2 N=2048 E=2048 H=16 G=4 D=128 HID=8192
// out = [ x2 (8.39M f32) | k_flat (8.39M) | v_flat (8.39M) | attn (134.2M) ]
// R1: global_load_lds width-16 staging in all MFMA GEMMs (m97 structure).
// ---------------------------------------------------------------------------

using f32x4  = __attribute__((ext_vector_type(4))) float;
using bf16x8 = __attribute__((ext_vector_type(8))) short;
using u16x4  = __attribute__((ext_vector_type(4))) unsigned short;

#define DEV __device__ __forceinline__

// async global->LDS, 16B per lane; LDS dest must be wave-uniform base + lane*16
#define ASYNC16(lds, g)                                                        \
  __builtin_amdgcn_global_load_lds(                                           \
      (const __attribute__((address_space(1))) void*)(g),                      \
      (__attribute__((address_space(3))) void*)(lds), 16, 0, 0)

DEV unsigned short f2bf(float f) {
  unsigned int u = __float_as_uint(f);
  return (unsigned short)((u + 0x7fffu + ((u >> 16) & 1u)) >> 16);
}
DEV float bf2f(unsigned short h) {
  return __uint_as_float(((unsigned int)h) << 16);
}

DEV float waveRedMax(float v) {
#pragma unroll
  for (int o = 32; o; o >>= 1) v = fmaxf(v, __shfl_xor(v, o));
  return v;
}
DEV float waveRedSum(float v) {
#pragma unroll
  for (int o = 32; o; o >>= 1) v += __shfl_xor(v, o);
  return v;
}

// ---- transpose+convert: in f32 [K,N] -> out bf16 [N,K] ---------------------
__global__ __launch_bounds__(256) void kconvT(const float* __restrict__ in,
                                              unsigned short* __restrict__ out,
                                              int K, int N) {
  __shared__ float tile[32][33];
  int bx = blockIdx.x * 32;  // N dim
  int by = blockIdx.y * 32;  // K dim
  int tx = threadIdx.x & 31;
  int ty = threadIdx.x >> 5;  // 0..7
#pragma unroll
  for (int i = 0; i < 32; i += 8)
    tile[ty + i][tx] = in[(size_t)(by + ty + i) * N + bx + tx];
  __syncthreads();
#pragma unroll
  for (int i = 0; i < 32; i += 8)
    out[(size_t)(bx + ty + i) * K + by + tx] = f2bf(tile[tx][ty + i]);
}

// ---- v_flat = x (f32 copy) and x_bf16 --------------------------------------
__global__ __launch_bounds__(256) void kcopy(const f32x4* __restrict__ x,
                                             f32x4* __restrict__ v,
                                             u16x4* __restrict__ xb) {
  int i = blockIdx.x * 256 + threadIdx.x;  // exactly 2,097,152 threads
  f32x4 val = x[i];
  v[i] = val;
  u16x4 o;
  o[0] = f2bf(val[0]); o[1] = f2bf(val[1]); o[2] = f2bf(val[2]); o[3] = f2bf(val[3]);
  xb[i] = o;
}

// ---- RoPE on per-head slices of x -> k_flat f32 (d_out) + xq bf16 ----------
__global__ __launch_bounds__(256) void krope(const float* __restrict__ x,
                                             float* __restrict__ kout,
                                             unsigned short* __restrict__ xq) {
  int idx = blockIdx.x * 256 + threadIdx.x;  // B*N*H*64 = 4,194,304
  int f  = idx & 63;
  int h  = (idx >> 6) & 15;
  int bn = idx >> 10;          // b*2048+n
  int n  = bn & 2047;
  size_t base = (size_t)bn * 2048 + h * 128;
  // 10000^(-f/64) = 2^(-f * log2(10000)/64)
  float inv = exp2f((float)f * (-13.287712379549449f / 64.0f));
  float ang = (float)n * inv;
  float c = cosf(ang), s = sinf(ang);
  float a = x[base + f], b = x[base + f + 64];
  float k1 = a * c - b * s;
  float k2 = b * c + a * s;
  kout[base + f]      = k1;
  kout[base + f + 64] = k2;
  xq[base + f]      = f2bf(k1);
  xq[base + f + 64] = f2bf(k2);
}

// ---- row softmax in-place, row = 2048 f32 ----------------------------------
__global__ __launch_bounds__(256) void ksoftmax(float* __restrict__ attn) {
  float* p = attn + (size_t)blockIdx.x * 2048;
  int tid = threadIdx.x;
  f32x4* p4 = (f32x4*)p;
  f32x4 v0 = p4[tid * 2], v1 = p4[tid * 2 + 1];
  float m = -3.4e38f;
#pragma unroll
  for (int i = 0; i < 4; ++i) { m = fmaxf(m, v0[i]); m = fmaxf(m, v1[i]); }
  m = waveRedMax(m);
  __shared__ float red[8];
  int wid = tid >> 6, lane = tid & 63;
  if (!lane) red[wid] = m;
  __syncthreads();
  m = fmaxf(fmaxf(red[0], red[1]), fmaxf(red[2], red[3]));
  float s = 0.f;
#pragma unroll
  for (int i = 0; i < 4; ++i) {
    v0[i] = expf(v0[i] - m); s += v0[i];
    v1[i] = expf(v1[i] - m); s += v1[i];
  }
  s = waveRedSum(s);
  if (!lane) red[4 + wid] = s;
  __syncthreads();
  s = red[4] + red[5] + red[6] + red[7];
  float invs = 1.0f / s;
  p4[tid * 2]     = v0 * invs;
  p4[tid * 2 + 1] = v1 * invs;
}

// ---- x1b = bf16(rmsnorm(x + ao) * w) ---------------------------------------
__global__ __launch_bounds__(256) void krms1(const float* __restrict__ x,
                                             const float* __restrict__ ao,
                                             const float* __restrict__ w,
                                             unsigned short* __restrict__ x1b) {
  size_t row = blockIdx.x;
  const f32x4* xp = (const f32x4*)(x + row * 2048);
  const f32x4* ap = (const f32x4*)(ao + row * 2048);
  int tid = threadIdx.x;
  f32x4 t0 = xp[tid * 2] + ap[tid * 2];
  f32x4 t1 = xp[tid * 2 + 1] + ap[tid * 2 + 1];
  float ss = 0.f;
#pragma unroll
  for (int i = 0; i < 4; ++i) ss += t0[i] * t0[i] + t1[i] * t1[i];
  ss = waveRedSum(ss);
  __shared__ float red[4];
  int wid = tid >> 6, lane = tid & 63;
  if (!lane) red[wid] = ss;
  __syncthreads();
  ss = red[0] + red[1] + red[2] + red[3];
  float rr = rsqrtf(ss * (1.0f / 2048.0f) + 1e-6f);
  const f32x4* wp = (const f32x4*)w;
  f32x4 w0 = wp[tid * 2], w1 = wp[tid * 2 + 1];
  u16x4 o0, o1;
#pragma unroll
  for (int i = 0; i < 4; ++i) {
    o0[i] = f2bf(t0[i] * rr * w0[i]);
    o1[i] = f2bf(t1[i] * rr * w1[i]);
  }
  u16x4* op = (u16x4*)(x1b + row * 2048);
  op[tid * 2] = o0;
  op[tid * 2 + 1] = o1;
}

// ---- x2 = f32(rmsnorm(x1b + fc) * w) -> d_out ------------------------------
__global__ __launch_bounds__(256) void krms2(const unsigned short* __restrict__ x1b,
                                             const unsigned short* __restrict__ fc,
                                             const float* __restrict__ w,
                                             float* __restrict__ out) {
  size_t row = blockIdx.x;
  const u16x4* xp = (const u16x4*)(x1b + row * 2048);
  const u16x4* fp = (const u16x4*)(fc + row * 2048);
  int tid = threadIdx.x;
  u16x4 a0 = xp[tid * 2], a1 = xp[tid * 2 + 1];
  u16x4 b0 = fp[tid * 2], b1 = fp[tid * 2 + 1];
  f32x4 t0, t1;
#pragma unroll
  for (int i = 0; i < 4; ++i) {
    t0[i] = bf2f(a0[i]) + bf2f(b0[i]);
    t1[i] = bf2f(a1[i]) + bf2f(b1[i]);
  }
  float ss = 0.f;
#pragma unroll
  for (int i = 0; i < 4; ++i) ss += t0[i] * t0[i] + t1[i] * t1[i];
  ss = waveRedSum(ss);
  __shared__ float red[4];
  int wid = tid >> 6, lane = tid & 63;
  if (!lane) red[wid] = ss;
  __syncthreads();
  ss = red[0] + red[1] + red[2] + red[3];
  float rr = rsqrtf(ss * (1.0f / 2048.0f) + 1e-6f);
  const f32x4* wp = (const f32x4*)w;
  f32x4 w0 = wp[tid * 2], w1 = wp[tid * 2 + 1];
  f32x4* op = (f32x4*)(out + row * 2048);
  op[tid * 2]     = t0 * rr * w0;
  op[tid * 2 + 1] = t1 * rr * w1;
}

// ---- generic 128x128 MFMA GEMM: C = alpha * A[M,K] @ BT[N,K]^T -------------
// Batched over z: b = z>>4, h = z&15; per-operand offsets.
// Staging via global_load_lds width=16 (LDS layout is linear in tid*16B).
template <bool A_F32, bool OUT_BF16, bool TRANS_OUT>
__global__ __launch_bounds__(256, 2) void gemm_bt(
    const void* __restrict__ A_, const unsigned short* __restrict__ Bt,
    void* __restrict__ C_, int K, int lda, int ldb, int ldc,
    long long oAb, long long oAh, long long oBb, long long oBg,
    long long oCb, long long oCh, float alpha) {
  __shared__ unsigned short As[128 * 32];
  __shared__ unsigned short Bs[128 * 32];
  const int tid = threadIdx.x;
  const int z = blockIdx.z, bz = z >> 4, hz = z & 15;
  const int bm0 = blockIdx.y * 128, bn0 = blockIdx.x * 128;
  const size_t offA = (size_t)(bz * oAb + hz * oAh);
  const size_t offB = (size_t)(bz * oBb + (hz >> 2) * oBg);
  const size_t offC = (size_t)(bz * oCb + hz * oCh);
  const unsigned short* Ab = (const unsigned short*)A_ + offA;
  const float* Af = (const float*)A_ + offA;
  const unsigned short* Bb = Bt + offB;

  f32x4 acc[4][4] = {};

  const int lane = tid & 63, wid = tid >> 6;
  const int wr = wid >> 1, wc = wid & 1;
  const int lr = lane & 15, kq = lane >> 4;
  const int srow = tid >> 2;        // 0..63
  const int scol = (tid & 3) * 8;   // 0,8,16,24
  unsigned short* AsW = As + tid * 8;  // byte offset tid*16, linear per wave
  unsigned short* BsW = Bs + tid * 8;

  for (int kt = 0; kt < K; kt += 32) {
    if constexpr (!A_F32) {
      ASYNC16(AsW,        Ab + (size_t)(bm0 + srow)      * lda + kt + scol);
      ASYNC16(AsW + 2048, Ab + (size_t)(bm0 + srow + 64) * lda + kt + scol);
    } else {
#pragma unroll
      for (int r = 0; r < 2; ++r) {
        int row = srow + 64 * r;
        const float* p = Af + (size_t)(bm0 + row) * lda + kt + scol;
        f32x4 lo = *(const f32x4*)p;
        f32x4 hi = *(const f32x4*)(p + 4);
        bf16x8 v;
        v[0] = (short)f2bf(lo[0]); v[1] = (short)f2bf(lo[1]);
        v[2] = (short)f2bf(lo[2]); v[3] = (short)f2bf(lo[3]);
        v[4] = (short)f2bf(hi[0]); v[5] = (short)f2bf(hi[1]);
        v[6] = (short)f2bf(hi[2]); v[7] = (short)f2bf(hi[3]);
        *(bf16x8*)&As[row * 32 + scol] = v;
      }
    }
    ASYNC16(BsW,        Bb + (size_t)(bn0 + srow)      * ldb + kt + scol);
    ASYNC16(BsW + 2048, Bb + (size_t)(bn0 + srow + 64) * ldb + kt + scol);
    __syncthreads();
    bf16x8 afr[4], bfr[4];
#pragma unroll
    for (int i = 0; i < 4; ++i)
      afr[i] = *(const bf16x8*)&As[(wr * 64 + i * 16 + lr) * 32 + kq * 8];
#pragma unroll
    for (int j = 0; j < 4; ++j)
      bfr[j] = *(const bf16x8*)&Bs[(wc * 64 + j * 16 + lr) * 32 + kq * 8];
#pragma unroll
    for (int i = 0; i < 4; ++i)
#pragma unroll
      for (int j = 0; j < 4; ++j)
        acc[i][j] = __builtin_amdgcn_mfma_f32_16x16x32_bf16(afr[i], bfr[j],
                                                            acc[i][j], 0, 0, 0);
    __syncthreads();
  }

#pragma unroll
  for (int i = 0; i < 4; ++i)
#pragma unroll
    for (int j = 0; j < 4; ++j) {
      int rowb = bm0 + wr * 64 + i * 16 + kq * 4;
      int col = bn0 + wc * 64 + j * 16 + lr;
#pragma unroll
      for (int r = 0; r < 4; ++r) {
        float v = acc[i][j][r] * alpha;
        size_t idx = TRANS_OUT ? ((size_t)col * ldc + (rowb + r))
                               : ((size_t)(rowb + r) * ldc + col);
        if constexpr (OUT_BF16)
          ((unsigned short*)C_)[offC + idx] = f2bf(v);
        else
          ((float*)C_)[offC + idx] = v;
      }
    }
}

// ---- fused GeGLU dual GEMM: h = (A@B1^T) * gelu(A@B2^T), bf16 out ----------
__global__ __launch_bounds__(256, 2) void gemm_geglu(
    const unsigned short* __restrict__ A, const unsigned short* __restrict__ B1,
    const unsigned short* __restrict__ B2, unsigned short* __restrict__ H_,
    int K, int lda, int ldb, int ldc) {
  __shared__ unsigned short As[128 * 32];
  __shared__ unsigned short B1s[128 * 32];
  __shared__ unsigned short B2s[128 * 32];
  const int tid = threadIdx.x;
  const int bm0 = blockIdx.y * 128, bn0 = blockIdx.x * 128;

  f32x4 accu[4][4] = {};
  f32x4 accg[4][4] = {};

  const int lane = tid & 63, wid = tid >> 6;
  const int wr = wid >> 1, wc = wid & 1;
  const int lr = lane & 15, kq = lane >> 4;
  const int srow = tid >> 2;
  const int scol = (tid & 3) * 8;
  unsigned short* AsW  = As + tid * 8;
  unsigned short* B1sW = B1s + tid * 8;
  unsigned short* B2sW = B2s + tid * 8;

  for (int kt = 0; kt < K; kt += 32) {
    ASYNC16(AsW,         A  + (size_t)(bm0 + srow)      * lda + kt + scol);
    ASYNC16(AsW + 2048,  A  + (size_t)(bm0 + srow + 64) * lda + kt + scol);
    ASYNC16(B1sW,        B1 + (size_t)(bn0 + srow)      * ldb + kt + scol);
    ASYNC16(B1sW + 2048, B1 + (size_t)(bn0 + srow + 64) * ldb + kt + scol);
    ASYNC16(B2sW,        B2 + (size_t)(bn0 + srow)      * ldb + kt + scol);
    ASYNC16(B2sW + 2048, B2 + (size_t)(bn0 + srow + 64) * ldb + kt + scol);
    __syncthreads();
    bf16x8 afr[4], b1fr[4], b2fr[4];
#pragma unroll
    for (int i = 0; i < 4; ++i)
      afr[i] = *(const bf16x8*)&As[(wr * 64 + i * 16 + lr) * 32 + kq * 8];
#pragma unroll
    for (int j = 0; j < 4; ++j) {
      b1fr[j] = *(const bf16x8*)&B1s[(wc * 64 + j * 16 + lr) * 32 + kq * 8];
      b2fr[j] = *(const bf16x8*)&B2s[(wc * 64 + j * 16 + lr) * 32 + kq * 8];
    }
#pragma unroll
    for (int i = 0; i < 4; ++i)
#pragma unroll
      for (int j = 0; j < 4; ++j) {
        accu[i][j] = __builtin_amdgcn_mfma_f32_16x16x32_bf16(afr[i], b1fr[j],
                                                             accu[i][j], 0, 0, 0);
        accg[i][j] = __builtin_amdgcn_mfma_f32_16x16x32_bf16(afr[i], b2fr[j],
                                                             accg[i][j], 0, 0, 0);
      }
    __syncthreads();
  }

#pragma unroll
  for (int i = 0; i < 4; ++i)
#pragma unroll
    for (int j = 0; j < 4; ++j) {
      int rowb = bm0 + wr * 64 + i * 16 + kq * 4;
      int col = bn0 + wc * 64 + j * 16 + lr;
#pragma unroll
      for (int r = 0; r < 4; ++r) {
        float u = accu[i][j][r];
        float g = accg[i][j][r];
        float t = tanhf(0.7978845608028654f * (g + 0.044715f * g * g * g));
        float hv = u * 0.5f * g * (1.0f + t);
        H_[(size_t)(rowb + r) * ldc + col] = f2bf(hv);
      }
    }
}

// ---------------------------------------------------------------------------
extern "C" void kernel_launch(void* const* d_in, const int* in_sizes, int n_in,
                              void* d_out, int out_size, void* d_ws, size_t ws_size,
                              hipStream_t stream) {
  const float* x   = (const float*)d_in[0];
  const float* wq  = (const float*)d_in[1];
  const float* wk  = (const float*)d_in[2];
  const float* wv  = (const float*)d_in[3];
  const float* wo  = (const float*)d_in[4];
  const float* w1  = (const float*)d_in[5];
  const float* w2  = (const float*)d_in[6];
  const float* n1w = (const float*)d_in[7];
  const float* n2w = (const float*)d_in[8];

  float* out    = (float*)d_out;
  float* x2_out = out;
  float* k_out  = out + 8388608;
  float* v_out  = out + 16777216;
  float* attn   = out + 25165824;  // 134,217,728 f32

  char* ws = (char*)d_ws;
  unsigned short* wqT  = (unsigned short*)(ws + 0);
  unsigned short* wkT  = (unsigned short*)(ws + 8388608);
  unsigned short* wvT  = (unsigned short*)(ws + 10485760);
  unsigned short* woT  = (unsigned short*)(ws + 12582912);
  unsigned short* w1T  = (unsigned short*)(ws + 20971520);
  unsigned short* w2T  = (unsigned short*)(ws + 88080384);
  unsigned short* qh   = (unsigned short*)(ws + 121634816);
  unsigned short* kh   = (unsigned short*)(ws + 138412032);
  unsigned short* vhT  = (unsigned short*)(ws + 142606336);
  unsigned short* ctx  = (unsigned short*)(ws + 146800640);
  float*          ao   = (float*)(ws + 163577856);
  unsigned short* hbuf = (unsigned short*)(ws + 121634816);  // alias qh..ao (dead)
  unsigned short* x1b  = (unsigned short*)(ws + 197132288);
  unsigned short* fc   = (unsigned short*)(ws + 213909504);
  // ws total: 230,686,720 bytes

  // bf16 scratch inside not-yet-written attn region of d_out
  unsigned short* xb = (unsigned short*)attn;   // bf16(x), 8,388,608 elems
  unsigned short* xq = xb + 8388608;            // bf16(rope(x))

  dim3 blk(256);

  // 1) weight convert+transpose (f32 [K,N] -> bf16 [N,K])
  kconvT<<<dim3(64, 64), blk, 0, stream>>>(wq, wqT, 2048, 2048);
  kconvT<<<dim3(16, 64), blk, 0, stream>>>(wk, wkT, 2048, 512);
  kconvT<<<dim3(16, 64), blk, 0, stream>>>(wv, wvT, 2048, 512);
  kconvT<<<dim3(64, 64), blk, 0, stream>>>(wo, woT, 2048, 2048);
  kconvT<<<dim3(512, 64), blk, 0, stream>>>(w1, w1T, 2048, 16384);
  kconvT<<<dim3(64, 256), blk, 0, stream>>>(w2, w2T, 8192, 2048);

  // 2) v_flat = x ; xb = bf16(x)
  kcopy<<<8192, blk, 0, stream>>>((const f32x4*)x, (f32x4*)v_out, (u16x4*)xb);
  // 3) k_flat = rope(x) f32 ; xq = bf16(rope(x))
  krope<<<16384, blk, 0, stream>>>(x, k_out, xq);

  // 4) projections
  gemm_bt<false, true, false><<<dim3(16, 32, 1), blk, 0, stream>>>(
      xq, wqT, qh, 2048, 2048, 2048, 2048, 0, 0, 0, 0, 0, 0, 1.0f);
  gemm_bt<false, true, false><<<dim3(4, 32, 1), blk, 0, stream>>>(
      xq, wkT, kh, 2048, 2048, 2048, 512, 0, 0, 0, 0, 0, 0, 1.0f);
  gemm_bt<false, true, true><<<dim3(4, 32, 1), blk, 0, stream>>>(
      xb, wvT, vhT, 2048, 2048, 2048, 4096, 0, 0, 0, 0, 0, 0, 1.0f);

  // 5) scores (raw -> attn region, f32), batched over (b,h)
  gemm_bt<false, false, false><<<dim3(16, 16, 32), blk, 0, stream>>>(
      qh, kh, attn, 128, 2048, 512, 2048,
      4194304LL, 128LL, 1048576LL, 128LL, 67108864LL, 4194304LL,
      0.08838834764831845f);
  // 6) softmax in-place
  ksoftmax<<<65536, blk, 0, stream>>>(attn);
  // 7) ctx = attn @ V  (A is f32, converted during staging; B via gll16)
  gemm_bt<true, true, false><<<dim3(1, 16, 32), blk, 0, stream>>>(
      attn, vhT, ctx, 2048, 2048, 4096, 2048,
      67108864LL, 4194304LL, 2048LL, 524288LL, 4194304LL, 128LL, 1.0f);
  // 8) attn_out = ctx @ wo (f32)
  gemm_bt<false, false, false><<<dim3(16, 32, 1), blk, 0, stream>>>(
      ctx, woT, ao, 2048, 2048, 2048, 2048, 0, 0, 0, 0, 0, 0, 1.0f);
  // 9) x1b = rmsnorm(x + ao) * n1w
  krms1<<<4096, blk, 0, stream>>>(x, ao, n1w, x1b);
  // 10) h = u * gelu(gate)  (fused dual GEMM, uv never materialized)
  gemm_geglu<<<dim3(64, 32, 1), blk, 0, stream>>>(x1b, w1T, w1T + 16777216,
                                                  hbuf, 2048, 2048, 2048, 8192);
  // 11) fc = h @ w2
  gemm_bt<false, true, false><<<dim3(16, 32, 1), blk, 0, stream>>>(
      hbuf, w2T, fc, 8192, 8192, 8192, 2048, 0, 0, 0, 0, 0, 0, 1.0f);
  // 12) x2 = rmsnorm(x1 + fc) * n2w
  krms2<<<4096, blk, 0, stream>>>(x1b, fc, n2w, x2_out);
}

// Round 3
// 1310.765 us; speedup vs baseline: 1.0412x; 1.0103x over previous
//
#include <hip/hip_runtime.h>
#include <hip/hip_bf16.h>

// ---------------------------------------------------------------------------
// TransformerBlock: B=2 N=2048 E=2048 H=16 G=4 D=128 HID=8192
// out = [ x2 (8.39M f32) | k_flat (8.39M) | v_flat (8.39M) | attn (134.2M) ]
// R2: 256x128 8-wave dbuf GEMM (front-loaded gll16 + XOR swizzle + setprio)
//     for GeGLU / fc / q-proj / wo. Small/odd GEMMs stay on 128^2 gemm_bt.
// ---------------------------------------------------------------------------

using f32x4  = __attribute__((ext_vector_type(4))) float;
using bf16x8 = __attribute__((ext_vector_type(8))) short;
using u16x4  = __attribute__((ext_vector_type(4))) unsigned short;

#define DEV __device__ __forceinline__

// async global->LDS, 16B per lane; LDS dest must be wave-uniform base + lane*16
#define ASYNC16(lds, g)                                                        \
  __builtin_amdgcn_global_load_lds(                                           \
      (const __attribute__((address_space(1))) void*)(g),                      \
      (__attribute__((address_space(3))) void*)(lds), 16, 0, 0)

DEV unsigned short f2bf(float f) {
  unsigned int u = __float_as_uint(f);
  return (unsigned short)((u + 0x7fffu + ((u >> 16) & 1u)) >> 16);
}
DEV float bf2f(unsigned short h) {
  return __uint_as_float(((unsigned int)h) << 16);
}

DEV float waveRedMax(float v) {
#pragma unroll
  for (int o = 32; o; o >>= 1) v = fmaxf(v, __shfl_xor(v, o));
  return v;
}
DEV float waveRedSum(float v) {
#pragma unroll
  for (int o = 32; o; o >>= 1) v += __shfl_xor(v, o);
  return v;
}

// ---- transpose+convert: in f32 [K,N] -> out bf16 [N,K] ---------------------
__global__ __launch_bounds__(256) void kconvT(const float* __restrict__ in,
                                              unsigned short* __restrict__ out,
                                              int K, int N) {
  __shared__ float tile[32][33];
  int bx = blockIdx.x * 32;  // N dim
  int by = blockIdx.y * 32;  // K dim
  int tx = threadIdx.x & 31;
  int ty = threadIdx.x >> 5;  // 0..7
#pragma unroll
  for (int i = 0; i < 32; i += 8)
    tile[ty + i][tx] = in[(size_t)(by + ty + i) * N + bx + tx];
  __syncthreads();
#pragma unroll
  for (int i = 0; i < 32; i += 8)
    out[(size_t)(bx + ty + i) * K + by + tx] = f2bf(tile[tx][ty + i]);
}

// ---- v_flat = x (f32 copy) and x_bf16 --------------------------------------
__global__ __launch_bounds__(256) void kcopy(const f32x4* __restrict__ x,
                                             f32x4* __restrict__ v,
                                             u16x4* __restrict__ xb) {
  int i = blockIdx.x * 256 + threadIdx.x;  // exactly 2,097,152 threads
  f32x4 val = x[i];
  v[i] = val;
  u16x4 o;
  o[0] = f2bf(val[0]); o[1] = f2bf(val[1]); o[2] = f2bf(val[2]); o[3] = f2bf(val[3]);
  xb[i] = o;
}

// ---- RoPE on per-head slices of x -> k_flat f32 (d_out) + xq bf16 ----------
__global__ __launch_bounds__(256) void krope(const float* __restrict__ x,
                                             float* __restrict__ kout,
                                             unsigned short* __restrict__ xq) {
  int idx = blockIdx.x * 256 + threadIdx.x;  // B*N*H*64 = 4,194,304
  int f  = idx & 63;
  int h  = (idx >> 6) & 15;
  int bn = idx >> 10;          // b*2048+n
  int n  = bn & 2047;
  size_t base = (size_t)bn * 2048 + h * 128;
  float inv = exp2f((float)f * (-13.287712379549449f / 64.0f));
  float ang = (float)n * inv;
  float c = cosf(ang), s = sinf(ang);
  float a = x[base + f], b = x[base + f + 64];
  float k1 = a * c - b * s;
  float k2 = b * c + a * s;
  kout[base + f]      = k1;
  kout[base + f + 64] = k2;
  xq[base + f]      = f2bf(k1);
  xq[base + f + 64] = f2bf(k2);
}

// ---- row softmax in-place, row = 2048 f32 ----------------------------------
__global__ __launch_bounds__(256) void ksoftmax(float* __restrict__ attn) {
  float* p = attn + (size_t)blockIdx.x * 2048;
  int tid = threadIdx.x;
  f32x4* p4 = (f32x4*)p;
  f32x4 v0 = p4[tid * 2], v1 = p4[tid * 2 + 1];
  float m = -3.4e38f;
#pragma unroll
  for (int i = 0; i < 4; ++i) { m = fmaxf(m, v0[i]); m = fmaxf(m, v1[i]); }
  m = waveRedMax(m);
  __shared__ float red[8];
  int wid = tid >> 6, lane = tid & 63;
  if (!lane) red[wid] = m;
  __syncthreads();
  m = fmaxf(fmaxf(red[0], red[1]), fmaxf(red[2], red[3]));
  float s = 0.f;
#pragma unroll
  for (int i = 0; i < 4; ++i) {
    v0[i] = expf(v0[i] - m); s += v0[i];
    v1[i] = expf(v1[i] - m); s += v1[i];
  }
  s = waveRedSum(s);
  if (!lane) red[4 + wid] = s;
  __syncthreads();
  s = red[4] + red[5] + red[6] + red[7];
  float invs = 1.0f / s;
  p4[tid * 2]     = v0 * invs;
  p4[tid * 2 + 1] = v1 * invs;
}

// ---- x1b = bf16(rmsnorm(x + ao) * w) ---------------------------------------
__global__ __launch_bounds__(256) void krms1(const float* __restrict__ x,
                                             const float* __restrict__ ao,
                                             const float* __restrict__ w,
                                             unsigned short* __restrict__ x1b) {
  size_t row = blockIdx.x;
  const f32x4* xp = (const f32x4*)(x + row * 2048);
  const f32x4* ap = (const f32x4*)(ao + row * 2048);
  int tid = threadIdx.x;
  f32x4 t0 = xp[tid * 2] + ap[tid * 2];
  f32x4 t1 = xp[tid * 2 + 1] + ap[tid * 2 + 1];
  float ss = 0.f;
#pragma unroll
  for (int i = 0; i < 4; ++i) ss += t0[i] * t0[i] + t1[i] * t1[i];
  ss = waveRedSum(ss);
  __shared__ float red[4];
  int wid = tid >> 6, lane = tid & 63;
  if (!lane) red[wid] = ss;
  __syncthreads();
  ss = red[0] + red[1] + red[2] + red[3];
  float rr = rsqrtf(ss * (1.0f / 2048.0f) + 1e-6f);
  const f32x4* wp = (const f32x4*)w;
  f32x4 w0 = wp[tid * 2], w1 = wp[tid * 2 + 1];
  u16x4 o0, o1;
#pragma unroll
  for (int i = 0; i < 4; ++i) {
    o0[i] = f2bf(t0[i] * rr * w0[i]);
    o1[i] = f2bf(t1[i] * rr * w1[i]);
  }
  u16x4* op = (u16x4*)(x1b + row * 2048);
  op[tid * 2] = o0;
  op[tid * 2 + 1] = o1;
}

// ---- x2 = f32(rmsnorm(x1b + fc) * w) -> d_out ------------------------------
__global__ __launch_bounds__(256) void krms2(const unsigned short* __restrict__ x1b,
                                             const unsigned short* __restrict__ fc,
                                             const float* __restrict__ w,
                                             float* __restrict__ out) {
  size_t row = blockIdx.x;
  const u16x4* xp = (const u16x4*)(x1b + row * 2048);
  const u16x4* fp = (const u16x4*)(fc + row * 2048);
  int tid = threadIdx.x;
  u16x4 a0 = xp[tid * 2], a1 = xp[tid * 2 + 1];
  u16x4 b0 = fp[tid * 2], b1 = fp[tid * 2 + 1];
  f32x4 t0, t1;
#pragma unroll
  for (int i = 0; i < 4; ++i) {
    t0[i] = bf2f(a0[i]) + bf2f(b0[i]);
    t1[i] = bf2f(a1[i]) + bf2f(b1[i]);
  }
  float ss = 0.f;
#pragma unroll
  for (int i = 0; i < 4; ++i) ss += t0[i] * t0[i] + t1[i] * t1[i];
  ss = waveRedSum(ss);
  __shared__ float red[4];
  int wid = tid >> 6, lane = tid & 63;
  if (!lane) red[wid] = ss;
  __syncthreads();
  ss = red[0] + red[1] + red[2] + red[3];
  float rr = rsqrtf(ss * (1.0f / 2048.0f) + 1e-6f);
  const f32x4* wp = (const f32x4*)w;
  f32x4 w0 = wp[tid * 2], w1 = wp[tid * 2 + 1];
  f32x4* op = (f32x4*)(out + row * 2048);
  op[tid * 2]     = t0 * rr * w0;
  op[tid * 2 + 1] = t1 * rr * w1;
}

// ---- 128x128 MFMA GEMM (kept for small/odd shapes) -------------------------
template <bool A_F32, bool OUT_BF16, bool TRANS_OUT>
__global__ __launch_bounds__(256, 2) void gemm_bt(
    const void* __restrict__ A_, const unsigned short* __restrict__ Bt,
    void* __restrict__ C_, int K, int lda, int ldb, int ldc,
    long long oAb, long long oAh, long long oBb, long long oBg,
    long long oCb, long long oCh, float alpha) {
  __shared__ unsigned short As[128 * 32];
  __shared__ unsigned short Bs[128 * 32];
  const int tid = threadIdx.x;
  const int z = blockIdx.z, bz = z >> 4, hz = z & 15;
  const int bm0 = blockIdx.y * 128, bn0 = blockIdx.x * 128;
  const size_t offA = (size_t)(bz * oAb + hz * oAh);
  const size_t offB = (size_t)(bz * oBb + (hz >> 2) * oBg);
  const size_t offC = (size_t)(bz * oCb + hz * oCh);
  const unsigned short* Ab = (const unsigned short*)A_ + offA;
  const float* Af = (const float*)A_ + offA;
  const unsigned short* Bb = Bt + offB;

  f32x4 acc[4][4] = {};

  const int lane = tid & 63, wid = tid >> 6;
  const int wr = wid >> 1, wc = wid & 1;
  const int lr = lane & 15, kq = lane >> 4;
  const int srow = tid >> 2;        // 0..63
  const int scol = (tid & 3) * 8;   // 0,8,16,24
  unsigned short* AsW = As + tid * 8;
  unsigned short* BsW = Bs + tid * 8;

  for (int kt = 0; kt < K; kt += 32) {
    if constexpr (!A_F32) {
      ASYNC16(AsW,        Ab + (size_t)(bm0 + srow)      * lda + kt + scol);
      ASYNC16(AsW + 2048, Ab + (size_t)(bm0 + srow + 64) * lda + kt + scol);
    } else {
#pragma unroll
      for (int r = 0; r < 2; ++r) {
        int row = srow + 64 * r;
        const float* p = Af + (size_t)(bm0 + row) * lda + kt + scol;
        f32x4 lo = *(const f32x4*)p;
        f32x4 hi = *(const f32x4*)(p + 4);
        bf16x8 v;
        v[0] = (short)f2bf(lo[0]); v[1] = (short)f2bf(lo[1]);
        v[2] = (short)f2bf(lo[2]); v[3] = (short)f2bf(lo[3]);
        v[4] = (short)f2bf(hi[0]); v[5] = (short)f2bf(hi[1]);
        v[6] = (short)f2bf(hi[2]); v[7] = (short)f2bf(hi[3]);
        *(bf16x8*)&As[row * 32 + scol] = v;
      }
    }
    ASYNC16(BsW,        Bb + (size_t)(bn0 + srow)      * ldb + kt + scol);
    ASYNC16(BsW + 2048, Bb + (size_t)(bn0 + srow + 64) * ldb + kt + scol);
    __syncthreads();
    bf16x8 afr[4], bfr[4];
#pragma unroll
    for (int i = 0; i < 4; ++i)
      afr[i] = *(const bf16x8*)&As[(wr * 64 + i * 16 + lr) * 32 + kq * 8];
#pragma unroll
    for (int j = 0; j < 4; ++j)
      bfr[j] = *(const bf16x8*)&Bs[(wc * 64 + j * 16 + lr) * 32 + kq * 8];
#pragma unroll
    for (int i = 0; i < 4; ++i)
#pragma unroll
      for (int j = 0; j < 4; ++j)
        acc[i][j] = __builtin_amdgcn_mfma_f32_16x16x32_bf16(afr[i], bfr[j],
                                                            acc[i][j], 0, 0, 0);
    __syncthreads();
  }

#pragma unroll
  for (int i = 0; i < 4; ++i)
#pragma unroll
    for (int j = 0; j < 4; ++j) {
      int rowb = bm0 + wr * 64 + i * 16 + kq * 4;
      int col = bn0 + wc * 64 + j * 16 + lr;
#pragma unroll
      for (int r = 0; r < 4; ++r) {
        float v = acc[i][j][r] * alpha;
        size_t idx = TRANS_OUT ? ((size_t)col * ldc + (rowb + r))
                               : ((size_t)(rowb + r) * ldc + col);
        if constexpr (OUT_BF16)
          ((unsigned short*)C_)[offC + idx] = f2bf(v);
        else
          ((float*)C_)[offC + idx] = v;
      }
    }
}

// ===========================================================================
// 256x128 8-wave double-buffered GEMM, BK=64.
// - staging: global_load_lds 16B, all next-tile loads issued at tile top
//   (latency hidden under current tile's ~1000cy of MFMA; __syncthreads'
//   vmcnt(0) drain is then ~free)
// - LDS XOR swizzle: chunk c=(row*8+cc), content for logical (row,cc) lives
//   at cc^(row&7). Applied on global SOURCE (write side, rule: gll16 writes
//   linearly) and on ds_read address (read side). Kills the 16-way bank
//   conflict of 128B-stride fragment reads.
// - waves: 8 = 2M x 4N; per-wave C = 128x32 (FI=8, FJ=2 frags of 16x16).
// ===========================================================================
template <bool OUT_BF16>
__global__ __launch_bounds__(512, 2) void gemm256(
    const unsigned short* __restrict__ A, const unsigned short* __restrict__ Bt,
    void* __restrict__ C_, int K, int lda, int ldb, int ldc) {
  __shared__ unsigned short As[2][256 * 64];  // 64 KB
  __shared__ unsigned short Bs[2][128 * 64];  // 32 KB
  const int tid = threadIdx.x;
  const int bm0 = blockIdx.y * 256, bn0 = blockIdx.x * 128;
  const int lane = tid & 63, wid = tid >> 6;
  const int wr = wid >> 2, wc = wid & 3;
  const int lr = lane & 15, kq = lane >> 4;

  f32x4 acc[8][2] = {};

  // per-thread staging chunk descriptors (A: 4 rounds, B: 2 rounds)
  int sArow[4], sAcc[4], sBrow[2], sBcc[2];
#pragma unroll
  for (int R = 0; R < 4; ++R) {
    int c = R * 512 + tid;
    sArow[R] = c >> 3;
    sAcc[R]  = (c & 7) ^ (sArow[R] & 7);  // pre-swizzled source col-chunk
  }
#pragma unroll
  for (int R = 0; R < 2; ++R) {
    int c = R * 512 + tid;
    sBrow[R] = c >> 3;
    sBcc[R]  = (c & 7) ^ (sBrow[R] & 7);
  }

  auto stage = [&](int buf, int k0) {
#pragma unroll
    for (int R = 0; R < 4; ++R)
      ASYNC16(&As[buf][(R * 512 + tid) * 8],
              A + (size_t)(bm0 + sArow[R]) * lda + k0 + sAcc[R] * 8);
#pragma unroll
    for (int R = 0; R < 2; ++R)
      ASYNC16(&Bs[buf][(R * 512 + tid) * 8],
              Bt + (size_t)(bn0 + sBrow[R]) * ldb + k0 + sBcc[R] * 8);
  };

  const int NT = K >> 6;
  stage(0, 0);
  __syncthreads();
  int cur = 0;
  for (int t = 0; t < NT; ++t) {
    if (t + 1 < NT) stage(cur ^ 1, (t + 1) << 6);
    const unsigned short* Ac = As[cur];
    const unsigned short* Bc = Bs[cur];
    __builtin_amdgcn_s_setprio(1);
#pragma unroll
    for (int ks = 0; ks < 2; ++ks) {
      bf16x8 afr[8];
#pragma unroll
      for (int i = 0; i < 8; ++i) {
        int row = wr * 128 + i * 16 + lr;
        int cch = (ks * 4 + kq) ^ (row & 7);
        afr[i] = *(const bf16x8*)&Ac[(row * 8 + cch) * 8];
      }
#pragma unroll
      for (int j = 0; j < 2; ++j) {
        int brow = wc * 32 + j * 16 + lr;
        int cch = (ks * 4 + kq) ^ (brow & 7);
        bf16x8 bfr = *(const bf16x8*)&Bc[(brow * 8 + cch) * 8];
#pragma unroll
        for (int i = 0; i < 8; ++i)
          acc[i][j] = __builtin_amdgcn_mfma_f32_16x16x32_bf16(afr[i], bfr,
                                                              acc[i][j], 0, 0, 0);
      }
    }
    __builtin_amdgcn_s_setprio(0);
    __syncthreads();
    cur ^= 1;
  }

#pragma unroll
  for (int i = 0; i < 8; ++i)
#pragma unroll
    for (int j = 0; j < 2; ++j) {
      int rowb = bm0 + wr * 128 + i * 16 + kq * 4;
      int col = bn0 + wc * 32 + j * 16 + lr;
#pragma unroll
      for (int r = 0; r < 4; ++r) {
        if constexpr (OUT_BF16)
          ((unsigned short*)C_)[(size_t)(rowb + r) * ldc + col] = f2bf(acc[i][j][r]);
        else
          ((float*)C_)[(size_t)(rowb + r) * ldc + col] = acc[i][j][r];
      }
    }
}

// ---- same structure, dual-B GeGLU: h = (A@B1^T) * gelu(A@B2^T) -------------
__global__ __launch_bounds__(512, 2) void gemm_geglu256(
    const unsigned short* __restrict__ A, const unsigned short* __restrict__ B1,
    const unsigned short* __restrict__ B2, unsigned short* __restrict__ H_,
    int K, int lda, int ldb, int ldc) {
  __shared__ unsigned short As[2][256 * 64];   // 64 KB
  __shared__ unsigned short B1s[2][128 * 64];  // 32 KB
  __shared__ unsigned short B2s[2][128 * 64];  // 32 KB
  const int tid = threadIdx.x;
  const int bm0 = blockIdx.y * 256, bn0 = blockIdx.x * 128;
  const int lane = tid & 63, wid = tid >> 6;
  const int wr = wid >> 2, wc = wid & 3;
  const int lr = lane & 15, kq = lane >> 4;

  f32x4 accu[8][2] = {};
  f32x4 accg[8][2] = {};

  int sArow[4], sAcc[4], sBrow[2], sBcc[2];
#pragma unroll
  for (int R = 0; R < 4; ++R) {
    int c = R * 512 + tid;
    sArow[R] = c >> 3;
    sAcc[R]  = (c & 7) ^ (sArow[R] & 7);
  }
#pragma unroll
  for (int R = 0; R < 2; ++R) {
    int c = R * 512 + tid;
    sBrow[R] = c >> 3;
    sBcc[R]  = (c & 7) ^ (sBrow[R] & 7);
  }

  auto stage = [&](int buf, int k0) {
#pragma unroll
    for (int R = 0; R < 4; ++R)
      ASYNC16(&As[buf][(R * 512 + tid) * 8],
              A + (size_t)(bm0 + sArow[R]) * lda + k0 + sAcc[R] * 8);
#pragma unroll
    for (int R = 0; R < 2; ++R)
      ASYNC16(&B1s[buf][(R * 512 + tid) * 8],
              B1 + (size_t)(bn0 + sBrow[R]) * ldb + k0 + sBcc[R] * 8);
#pragma unroll
    for (int R = 0; R < 2; ++R)
      ASYNC16(&B2s[buf][(R * 512 + tid) * 8],
              B2 + (size_t)(bn0 + sBrow[R]) * ldb + k0 + sBcc[R] * 8);
  };

  const int NT = K >> 6;
  stage(0, 0);
  __syncthreads();
  int cur = 0;
  for (int t = 0; t < NT; ++t) {
    if (t + 1 < NT) stage(cur ^ 1, (t + 1) << 6);
    const unsigned short* Ac = As[cur];
    const unsigned short* B1c = B1s[cur];
    const unsigned short* B2c = B2s[cur];
    __builtin_amdgcn_s_setprio(1);
#pragma unroll
    for (int ks = 0; ks < 2; ++ks) {
      bf16x8 afr[8];
#pragma unroll
      for (int i = 0; i < 8; ++i) {
        int row = wr * 128 + i * 16 + lr;
        int cch = (ks * 4 + kq) ^ (row & 7);
        afr[i] = *(const bf16x8*)&Ac[(row * 8 + cch) * 8];
      }
#pragma unroll
      for (int j = 0; j < 2; ++j) {
        int brow = wc * 32 + j * 16 + lr;
        int cch = (ks * 4 + kq) ^ (brow & 7);
        bf16x8 b1 = *(const bf16x8*)&B1c[(brow * 8 + cch) * 8];
        bf16x8 b2 = *(const bf16x8*)&B2c[(brow * 8 + cch) * 8];
#pragma unroll
        for (int i = 0; i < 8; ++i) {
          accu[i][j] = __builtin_amdgcn_mfma_f32_16x16x32_bf16(afr[i], b1,
                                                               accu[i][j], 0, 0, 0);
          accg[i][j] = __builtin_amdgcn_mfma_f32_16x16x32_bf16(afr[i], b2,
                                                               accg[i][j], 0, 0, 0);
        }
      }
    }
    __builtin_amdgcn_s_setprio(0);
    __syncthreads();
    cur ^= 1;
  }

#pragma unroll
  for (int i = 0; i < 8; ++i)
#pragma unroll
    for (int j = 0; j < 2; ++j) {
      int rowb = bm0 + wr * 128 + i * 16 + kq * 4;
      int col = bn0 + wc * 32 + j * 16 + lr;
#pragma unroll
      for (int r = 0; r < 4; ++r) {
        float u = accu[i][j][r];
        float g = accg[i][j][r];
        float tv = tanhf(0.7978845608028654f * (g + 0.044715f * g * g * g));
        float hv = u * 0.5f * g * (1.0f + tv);
        H_[(size_t)(rowb + r) * ldc + col] = f2bf(hv);
      }
    }
}

// ---------------------------------------------------------------------------
extern "C" void kernel_launch(void* const* d_in, const int* in_sizes, int n_in,
                              void* d_out, int out_size, void* d_ws, size_t ws_size,
                              hipStream_t stream) {
  const float* x   = (const float*)d_in[0];
  const float* wq  = (const float*)d_in[1];
  const float* wk  = (const float*)d_in[2];
  const float* wv  = (const float*)d_in[3];
  const float* wo  = (const float*)d_in[4];
  const float* w1  = (const float*)d_in[5];
  const float* w2  = (const float*)d_in[6];
  const float* n1w = (const float*)d_in[7];
  const float* n2w = (const float*)d_in[8];

  float* out    = (float*)d_out;
  float* x2_out = out;
  float* k_out  = out + 8388608;
  float* v_out  = out + 16777216;
  float* attn   = out + 25165824;  // 134,217,728 f32

  char* ws = (char*)d_ws;
  unsigned short* wqT  = (unsigned short*)(ws + 0);
  unsigned short* wkT  = (unsigned short*)(ws + 8388608);
  unsigned short* wvT  = (unsigned short*)(ws + 10485760);
  unsigned short* woT  = (unsigned short*)(ws + 12582912);
  unsigned short* w1T  = (unsigned short*)(ws + 20971520);
  unsigned short* w2T  = (unsigned short*)(ws + 88080384);
  unsigned short* qh   = (unsigned short*)(ws + 121634816);
  unsigned short* kh   = (unsigned short*)(ws + 138412032);
  unsigned short* vhT  = (unsigned short*)(ws + 142606336);
  unsigned short* ctx  = (unsigned short*)(ws + 146800640);
  float*          ao   = (float*)(ws + 163577856);
  unsigned short* hbuf = (unsigned short*)(ws + 121634816);  // alias qh..ao (dead)
  unsigned short* x1b  = (unsigned short*)(ws + 197132288);
  unsigned short* fc   = (unsigned short*)(ws + 213909504);
  // ws total: 230,686,720 bytes

  // bf16 scratch inside not-yet-written attn region of d_out
  unsigned short* xb = (unsigned short*)attn;   // bf16(x), 8,388,608 elems
  unsigned short* xq = xb + 8388608;            // bf16(rope(x))

  dim3 blk(256);
  dim3 blk512(512);

  // 1) weight convert+transpose (f32 [K,N] -> bf16 [N,K])
  kconvT<<<dim3(64, 64), blk, 0, stream>>>(wq, wqT, 2048, 2048);
  kconvT<<<dim3(16, 64), blk, 0, stream>>>(wk, wkT, 2048, 512);
  kconvT<<<dim3(16, 64), blk, 0, stream>>>(wv, wvT, 2048, 512);
  kconvT<<<dim3(64, 64), blk, 0, stream>>>(wo, woT, 2048, 2048);
  kconvT<<<dim3(512, 64), blk, 0, stream>>>(w1, w1T, 2048, 16384);
  kconvT<<<dim3(64, 256), blk, 0, stream>>>(w2, w2T, 8192, 2048);

  // 2) v_flat = x ; xb = bf16(x)
  kcopy<<<8192, blk, 0, stream>>>((const f32x4*)x, (f32x4*)v_out, (u16x4*)xb);
  // 3) k_flat = rope(x) f32 ; xq = bf16(rope(x))
  krope<<<16384, blk, 0, stream>>>(x, k_out, xq);

  // 4) projections: q via gemm256, k/v via gemm_bt (N=512 too small for 256-tile grid)
  gemm256<true><<<dim3(16, 16), blk512, 0, stream>>>(
      xq, wqT, qh, 2048, 2048, 2048, 2048);
  gemm_bt<false, true, false><<<dim3(4, 32, 1), blk, 0, stream>>>(
      xq, wkT, kh, 2048, 2048, 2048, 512, 0, 0, 0, 0, 0, 0, 1.0f);
  gemm_bt<false, true, true><<<dim3(4, 32, 1), blk, 0, stream>>>(
      xb, wvT, vhT, 2048, 2048, 2048, 4096, 0, 0, 0, 0, 0, 0, 1.0f);

  // 5) scores (raw -> attn region, f32), batched over (b,h)
  gemm_bt<false, false, false><<<dim3(16, 16, 32), blk, 0, stream>>>(
      qh, kh, attn, 128, 2048, 512, 2048,
      4194304LL, 128LL, 1048576LL, 128LL, 67108864LL, 4194304LL,
      0.08838834764831845f);
  // 6) softmax in-place
  ksoftmax<<<65536, blk, 0, stream>>>(attn);
  // 7) ctx = attn @ V  (A is f32, converted during staging; B via gll16)
  gemm_bt<true, true, false><<<dim3(1, 16, 32), blk, 0, stream>>>(
      attn, vhT, ctx, 2048, 2048, 4096, 2048,
      67108864LL, 4194304LL, 2048LL, 524288LL, 4194304LL, 128LL, 1.0f);
  // 8) attn_out = ctx @ wo (f32)
  gemm256<false><<<dim3(16, 16), blk512, 0, stream>>>(
      ctx, woT, (void*)ao, 2048, 2048, 2048, 2048);
  // 9) x1b = rmsnorm(x + ao) * n1w
  krms1<<<4096, blk, 0, stream>>>(x, ao, n1w, x1b);
  // 10) h = u * gelu(gate)  (fused dual GEMM, uv never materialized)
  gemm_geglu256<<<dim3(64, 16), blk512, 0, stream>>>(
      x1b, w1T, w1T + 16777216, hbuf, 2048, 2048, 2048, 8192);
  // 11) fc = h @ w2
  gemm256<true><<<dim3(16, 16), blk512, 0, stream>>>(
      hbuf, w2T, fc, 8192, 8192, 8192, 2048);
  // 12) x2 = rmsnorm(x1 + fc) * n2w
  krms2<<<4096, blk, 0, stream>>>(x1b, fc, n2w, x2_out);
}